// Round 9
// baseline (261.945 us; speedup 1.0000x reference)
//
#include <hip/hip_runtime.h>
#include <cstddef>

#define NB 64
#define LL 512
#define HH 256
#define HD 128
#define NG 512
#define TI 16

typedef _Float16 half_t;
typedef _Float16 half8 __attribute__((ext_vector_type(8)));
typedef _Float16 half4 __attribute__((ext_vector_type(4)));
typedef float f32x4 __attribute__((ext_vector_type(4)));

#define MFMA16(a, b, c) __builtin_amdgcn_mfma_f32_16x16x32_f16((a), (b), (c), 0, 0, 0)

// LDS pitches (<=2-way bank aliasing, free on CDNA4)
#define FP 264   // sFeatb pitch (f16)
#define XP 518   // sXG pitch (f32); rows 0..18 used (max s+t = 15+3 = 18)
#define HBP 136  // sHb pitch (f16)
#define EP 17    // sE inner pitch (f32)

// fast gates: v_rcp_f32 (~1 ulp) instead of full-precision divide.
__device__ __forceinline__ float sigm(float x)  { return __builtin_amdgcn_rcpf(1.0f + __expf(-x)); }
__device__ __forceinline__ float tanhf_(float x){ return 2.0f * __builtin_amdgcn_rcpf(1.0f + __expf(-2.0f * x)) - 1.0f; }

// 16-lane (DPP-row) sum on the VALU pipe: no DS ops.
template <int CTRL>
__device__ __forceinline__ float dppadd(float x) {
    int v = __builtin_amdgcn_update_dpp(0, __float_as_int(x), CTRL, 0xF, 0xF, true);
    return x + __int_as_float(v);
}
__device__ __forceinline__ float row16_sum(float x) {
    x = dppadd<0xB1>(x);    // quad_perm [1,0,3,2]
    x = dppadd<0x4E>(x);    // quad_perm [2,3,0,1]
    x = dppadd<0x141>(x);   // row_half_mirror
    x = dppadd<0x140>(x);   // row_mirror
    return x;
}

// Barrier with LDS visibility but NO vmcnt drain.
__device__ __forceinline__ void barrier_lgkm() {
    asm volatile("s_waitcnt lgkmcnt(0)" ::: "memory");
    __builtin_amdgcn_s_barrier();
    asm volatile("" ::: "memory");
}

// ---- prep: cast weights to f16, bsum = b_ih + b_hh ----
__global__ void prep_weights(const float* __restrict__ Wih, const float* __restrict__ Whh,
                             const float* __restrict__ bih, const float* __restrict__ bhh,
                             half_t* __restrict__ WihH, half_t* __restrict__ WhhH,
                             float* __restrict__ bsum)
{
    const int idx = blockIdx.x * 256 + threadIdx.x;
    if (idx < NG * HH) WihH[idx] = (half_t)Wih[idx];
    if (idx < NG * HD) WhhH[idx] = (half_t)Whh[idx];
    if (idx < NG)      bsum[idx] = bih[idx] + bhh[idx];
}

// R9: back to single-batch R7 structure (R8 batch-pair halved concurrency 1:1
// with doubled work -- net loss). LDS cut 65->52.4 KB so 3 blocks/CU fit:
//   - sFeatb aliased inside sXG (one extra barrier after A-frag hoist; R1
//     proved safe at 60 VGPR -- the R2 spill was launch_bounds(512,6))
//   - sVal + finalize phase deleted (writers read sE partials directly)
// launch_bounds stays (512,4): known-good codegen (64 arch VGPR + bf2 in
// AGPRs = 128 budget); the 2nd arg only bounds the allocator, LDS sets
// the real cap at 3 blocks/CU = 24 waves/CU.
__global__ __launch_bounds__(512, 4) void span_lstm_mfma(
    const float* __restrict__ feats, const half_t* __restrict__ WihH,
    const half_t* __restrict__ WhhH, const float* __restrict__ bsum,
    const float* __restrict__ W_tri, const float* __restrict__ b_tri,
    const int* __restrict__ lens, float* __restrict__ out)
{
    // 39,368 (sXG; sFeatb 10,560 aliased inside) + 8,704 + 4,352 = 52,424 B
    __shared__ __align__(16) float  sXG[19 * XP];
    __shared__ __align__(16) half_t sHb[2][16 * HBP];
    __shared__ __align__(16) float  sE[4][16 * EP];   // [ts][s*EP + wv*2 + tag]

    half_t* sFeatb = (half_t*)sXG;   // dead after A-frag hoist (barrier-fenced)

    const int tid = threadIdx.x;
    const int b  = blockIdx.x >> 5;
    const int i0 = (blockIdx.x & 31) * TI;
    const int lens_b = lens[b];

    // ---- dead-block: all spans masked; memset already zeroed the slice ----
    if (i0 >= lens_b) return;

    const int lane = tid & 63, wv = tid >> 6;   // 8 waves
    const int lm = lane & 15;                   // m / n within 16-tile (DPP row-local)
    const int lq = lane >> 4;                   // quad
    const int jw = wv * 16;
    const int gcol = jw + lm;

    // ---- stage feats window (20 rows) as f16; rows >= lens_b are never
    // consumed by any SELECTED step (sel count <= rem => max row lens_b-1),
    // so they stage as zeros without loading. ----
    for (int idx = tid; idx < 20 * 64; idx += 512) {
        const int p  = idx >> 6;
        const int k4 = (idx & 63) << 2;
        const int gp = i0 + p;
        float4 v = make_float4(0.f, 0.f, 0.f, 0.f);
        if (gp < lens_b) v = *(const float4*)(feats + ((size_t)b * LL + gp) * HH + k4);
        half4 hv = {(half_t)v.x, (half_t)v.y, (half_t)v.z, (half_t)v.w};
        *(half4*)(&sFeatb[p * FP + k4]) = hv;
    }
    __syncthreads();

    // ---- hoist A-frags (2 M-tiles x 8 K-frags) then fence before sXG
    // overwrites the aliased feats region ----
    half8 afr[2][8];
    #pragma unroll
    for (int mt = 0; mt < 2; ++mt)
        #pragma unroll
        for (int kf = 0; kf < 8; ++kf)
            afr[mt][kf] = *(const half8*)(&sFeatb[(16 * mt + lm) * FP + kf * 32 + lq * 8]);
    __syncthreads();

    // ---- phase 1: wave computes XG only for ITS gate columns (4 ta x 16 cols);
    // sXG rows are wave-private -> no barrier before the t-loop ----
    #pragma unroll
    for (int ta = 0; ta < 4; ++ta) {
        const int gb = ta * HD + jw;
        const float bs = bsum[gb + lm];
        f32x4 acc0 = {0.f, 0.f, 0.f, 0.f}, acc1 = {0.f, 0.f, 0.f, 0.f};
        #pragma unroll
        for (int kf = 0; kf < 8; ++kf) {
            const half8 bfr = *(const half8*)(WihH + (size_t)(gb + lm) * HH + kf * 32 + lq * 8);
            acc0 = MFMA16(afr[0][kf], bfr, acc0);
            acc1 = MFMA16(afr[1][kf], bfr, acc1);
        }
        #pragma unroll
        for (int r = 0; r < 4; ++r)
            sXG[(lq * 4 + r) * XP + gb + lm] = acc0[r] + bs;
        if (lq == 0) {
            #pragma unroll
            for (int r = 0; r < 3; ++r)        // rows 16..18 (row 19 never read)
                sXG[(16 + r) * XP + gb + lm] = acc1[r] + bs;
        }
    }

    // ---- Whh B-frags: 4 ta x 4 kf for this wave's 16 columns (AGPR-backed) ----
    half8 bf2[4][4];
    #pragma unroll
    for (int ta = 0; ta < 4; ++ta)
        #pragma unroll
        for (int kf = 0; kf < 4; ++kf)
            bf2[ta][kf] = *(const half8*)(WhhH + (size_t)(ta * HD + gcol) * HD + kf * 32 + lq * 8);
    const float wt0 = W_tri[gcol];
    const float wt1 = W_tri[HD + gcol];
    const float bt0 = b_tri[0], bt1 = b_tri[1];

    float cc4[4] = {0.f, 0.f, 0.f, 0.f};
    float hhA[4][4];   // all 4 steps' h in f32 regs -> emission outside the loop

    // ---- recurrence: minimal barrier-locked body; raw barriers (no vmcnt drain) ----
    #pragma unroll
    for (int t = 0; t < 4; ++t) {
        float accg[4][4];
        if (t > 0) {
            half8 ah[4];
            #pragma unroll
            for (int kf = 0; kf < 4; ++kf)
                ah[kf] = *(const half8*)(&sHb[(t - 1) & 1][lm * HBP + kf * 32 + lq * 8]);
            #pragma unroll
            for (int ta = 0; ta < 4; ++ta) {
                f32x4 a = {0.f, 0.f, 0.f, 0.f};
                #pragma unroll
                for (int kf = 0; kf < 4; ++kf)
                    a = MFMA16(ah[kf], bf2[ta][kf], a);
                #pragma unroll
                for (int r = 0; r < 4; ++r) accg[ta][r] = a[r];
            }
        } else {
            #pragma unroll
            for (int ta = 0; ta < 4; ++ta)
                #pragma unroll
                for (int r = 0; r < 4; ++r) accg[ta][r] = 0.f;
        }
        #pragma unroll
        for (int ta = 0; ta < 4; ++ta)
            #pragma unroll
            for (int r = 0; r < 4; ++r)
                accg[ta][r] += sXG[(lq * 4 + r + t) * XP + ta * HD + gcol];

        #pragma unroll
        for (int r = 0; r < 4; ++r) {
            const float ig = sigm(accg[0][r]);
            const float fg = sigm(accg[1][r]);
            const float gg = tanhf_(accg[2][r]);
            const float og = sigm(accg[3][r]);
            cc4[r] = fg * cc4[r] + ig * gg;
            hhA[t][r] = og * tanhf_(cc4[r]);
        }

        if (t < 3) {
            #pragma unroll
            for (int r = 0; r < 4; ++r)
                sHb[t & 1][(lq * 4 + r) * HBP + gcol] = (half_t)hhA[t][r];
            barrier_lgkm();
        }
    }

    // ---- emission: DPP row-sums, f32-exact, outside the barrier cadence ----
    #pragma unroll
    for (int ts = 0; ts < 4; ++ts)
        #pragma unroll
        for (int r = 0; r < 4; ++r) {
            float e0 = row16_sum(hhA[ts][r] * wt0);
            float e1 = row16_sum(hhA[ts][r] * wt1);
            if (lm == 0) {
                float2 v = make_float2(e0, e1);
                *(float2*)&sE[ts][(lq * 4 + r) * EP + wv * 2] = v;
            }
        }
    barrier_lgkm();   // sE visible

    // ---- sparse value write, finalize merged in: <=3 16B chunks per live
    // row; each writer sums the 8 wave partials straight from sE ----
    if (tid < 48) {
        const int es = tid & 15, m = tid >> 4;   // m in 0..2
        const int i = i0 + es;
        const int rem = lens_b - i;
        if (rem > 0) {
            const int chi = ((i + 3 < LL) ? (i + 3) : (LL - 1)) >> 1;
            const int c = (i >> 1) + m;
            if (c <= chi) {
                const int j0 = 2 * c;
                f32x4 v = {0.f, 0.f, 0.f, 0.f};
                #pragma unroll
                for (int half = 0; half < 2; ++half) {
                    const int w = j0 + half - i + 1;
                    if ((unsigned)(w - 1) < 4u && (j0 + half) < LL) {
                        const int ts = (rem < w ? rem : w) - 1;
                        float e0 = bt0, e1 = bt1;
                        #pragma unroll
                        for (int k = 0; k < 8; ++k) {
                            e0 += sE[ts][es * EP + k * 2 + 0];
                            e1 += sE[ts][es * EP + k * 2 + 1];
                        }
                        if (half == 0) { v.x = e0; v.y = e1; }
                        else           { v.z = e0; v.w = e1; }
                    }
                }
                float* ob = out + ((size_t)b * LL + i0) * (LL * 2);
                *(f32x4*)(ob + ((size_t)es * 256 + c) * 4) = v;
            }
        }
    }
}

extern "C" void kernel_launch(void* const* d_in, const int* in_sizes, int n_in,
                              void* d_out, int out_size, void* d_ws, size_t ws_size,
                              hipStream_t stream)
{
    const float* feats = (const float*)d_in[0];
    const float* W_ih  = (const float*)d_in[1];
    const float* W_hh  = (const float*)d_in[2];
    const float* b_ih  = (const float*)d_in[3];
    const float* b_hh  = (const float*)d_in[4];
    const float* W_tri = (const float*)d_in[5];
    const float* b_tri = (const float*)d_in[6];
    const int*   lens  = (const int*)d_in[7];
    float* out = (float*)d_out;

    // Bulk zeros via the driver blit (~6 TB/s; in-kernel streams cap at ~1.1).
    hipMemsetAsync(out, 0, (size_t)out_size * sizeof(float), stream);

    // ws layout: WihH (256 KB) | WhhH (128 KB) | bsum (2 KB)
    half_t* WihH = (half_t*)d_ws;
    half_t* WhhH = WihH + (size_t)NG * HH;
    float*  bsum = (float*)(WhhH + (size_t)NG * HD);

    prep_weights<<<(NG * HH + 255) / 256, 256, 0, stream>>>(W_ih, W_hh, b_ih, b_hh,
                                                            WihH, WhhH, bsum);
    span_lstm_mfma<<<NB * (LL / TI), 512, 0, stream>>>(feats, WihH, WhhH, bsum,
                                                       W_tri, b_tri, lens, out);
}